// Round 5
// baseline (490.615 us; speedup 1.0000x reference)
//
#include <hip/hip_runtime.h>
#include <hip/hip_bf16.h>
#include <math.h>

namespace {

constexpr int B = 2;
constexpr int N = 8192;
constexpr int D = 64;
constexpr int GRID = 10;
constexpr int GC = GRID * GRID * GRID;     // 1000 cells per batch
constexpr int BUFK = 16;
constexpr float H = 0.1f;
constexpr float NEGS = 0.2f;
constexpr float BN_INV = 0.9999950000374997f;   // 1/sqrt(1+1e-5)
constexpr float RSQN = 0.011048543456039806f;   // 1/sqrt(8192)

typedef __attribute__((ext_vector_type(8))) short bf16x8;
typedef __attribute__((ext_vector_type(16))) float f32x16;

union Frag { int4 i4; unsigned u[4]; bf16x8 h; };

__device__ __forceinline__ float lrelu(float v) { return v > 0.f ? v : NEGS * v; }

__device__ __forceinline__ unsigned pk2(float a, float b) {
  __hip_bfloat162 h2 = __float22bfloat162_rn(make_float2(a, b));
  unsigned r;
  __builtin_memcpy(&r, &h2, 4);
  return r;
}
__device__ __forceinline__ float blo(unsigned u) { return __uint_as_float(u << 16); }
__device__ __forceinline__ float bhi(unsigned u) { return __uint_as_float(u & 0xFFFF0000u); }

__device__ __forceinline__ f32x16 MF(int4 a, const Frag& b, f32x16 c) {
  Frag af; af.i4 = a;
  return __builtin_amdgcn_mfma_f32_32x32x16_bf16(af.h, b.h, c, 0, 0, 0);
}

__device__ __forceinline__ int cellco(float v) {
  int c = (int)(v * 10.0f);
  return min(max(c, 0), GRID - 1);
}

// D-layout f32 (x0: chans 0-31 rows, x1: chans 32-63) -> B-fragments for next layer.
__device__ __forceinline__ void buildB(const f32x16& x0, const f32x16& x1, int h, Frag Bf[4]) {
  unsigned Z[8][2];
  #pragma unroll
  for (int q = 0; q < 4; ++q) {
    Z[q][0]     = pk2(x0[4*q+0], x0[4*q+1]);
    Z[q][1]     = pk2(x0[4*q+2], x0[4*q+3]);
    Z[4+q][0]   = pk2(x1[4*q+0], x1[4*q+1]);
    Z[4+q][1]   = pk2(x1[4*q+2], x1[4*q+3]);
  }
  unsigned S[8][2];
  #pragma unroll
  for (int q = 0; q < 8; ++q) {
    S[q][0] = (unsigned)__shfl_xor((int)Z[q][0], 32);
    S[q][1] = (unsigned)__shfl_xor((int)Z[q][1], 32);
  }
  #pragma unroll
  for (int t = 0; t < 4; ++t) {
    int qq = (t >> 1) * 4 + 2 * (t & 1);
    Bf[t].u[0] = h ? S[qq+1][0] : Z[qq][0];
    Bf[t].u[1] = h ? S[qq+1][1] : Z[qq][1];
    Bf[t].u[2] = h ? Z[qq+1][0] : S[qq][0];
    Bf[t].u[3] = h ? Z[qq+1][1] : S[qq][1];
  }
}

__device__ __forceinline__ f32x16 biasAct(f32x16 d, const float4* bp, int mt, int h) {
  f32x16 r;
  #pragma unroll
  for (int q = 0; q < 4; ++q) {
    float4 bb = bp[h * 8 + mt * 4 + q];
    r[4*q+0] = lrelu(d[4*q+0] + bb.x);
    r[4*q+1] = lrelu(d[4*q+1] + bb.y);
    r[4*q+2] = lrelu(d[4*q+2] + bb.z);
    r[4*q+3] = lrelu(d[4*q+3] + bb.w);
  }
  return r;
}

// ---------------- prep: pack A-fragments (bf16, BN scale folded) + permuted biases ----------------
struct PrepArgs {
  const float* W[9];       // W1,Wq,Wk,Wv,Wd2,Wg1,Wg2,W2,Wd1
  const float* scale[9];
  const float* bias[5];    // b1,bd2,bg1,bg2,b2
  const float* bd1;
};

__global__ __launch_bounds__(256) void prep_kernel(PrepArgs a, unsigned short* AF, float* biasAll) {
  int mi = blockIdx.x;
  int tid = threadIdx.x;
  if (mi < 8) {
    int off = (mi == 7) ? 29696 : mi * 4096;
    const float* W = a.W[mi];
    const float* G = a.scale[mi];
    unsigned short* dst = AF + off;
    for (int e = tid; e < 4096; e += 256) {
      int i = e & 7, lane = (e >> 3) & 63, t = (e >> 9) & 3, mt = e >> 11;
      int row = 32 * mt + (lane & 31);
      int k = 16 * t + 8 * (lane >> 5) + i;
      float v = W[row * 64 + k];
      if (G) v *= G[row] * BN_INV;
      __hip_bfloat16 hb = __float2bfloat16(v);
      __builtin_memcpy(&dst[e], &hb, 2);
    }
  } else {
    const float* W = a.W[8];
    const float* G = a.scale[8];
    for (int e = tid; e < 1024; e += 256) {
      int i = e & 7, lane = (e >> 3) & 63, mt = e >> 9;
      int row = 32 * mt + (lane & 31), h = lane >> 5;
      float v = 0.f;
      if (h == 0) {
        if (i < 3) v = W[row * 3 + i] * G[row] * BN_INV;
        else if (i == 3) v = a.bd1[row];
      }
      __hip_bfloat16 hb = __float2bfloat16(v);
      __builtin_memcpy(&AF[28672 + e], &hb, 2);
    }
    for (int e = tid; e < 320; e += 256) {
      int ai = e >> 6, idx = e & 63;
      int h = idx >> 5, mt = (idx >> 4) & 1, q = (idx >> 2) & 3, j = idx & 3;
      biasAll[e] = a.bias[ai][32 * mt + 8 * q + 4 * h + j];
    }
  }
}

// ---------------- pos4 + cell id + histogram ----------------
__global__ __launch_bounds__(256) void pos4cid_kernel(
    const float* __restrict__ pos, float* __restrict__ pos4,
    int* __restrict__ cid16, int* __restrict__ cellCount)
{
  int i = blockIdx.x * 256 + threadIdx.x;
  int b = i >> 13;
  int n = i & (N - 1);
  const float* pb = pos + (size_t)b * 3 * N;
  float x = pb[n], y = pb[N + n], z = pb[2 * N + n];
  float4 v = {x, y, z, x * x + y * y + z * z};
  *reinterpret_cast<float4*>(pos4 + (size_t)i * 4) = v;
  int cid = (cellco(z) * GRID + cellco(y)) * GRID + cellco(x);
  cid16[i] = cid;
  atomicAdd(&cellCount[b * GC + cid], 1);
}

// ---------------- scan: exclusive prefix over 2048 cell counts (single block) ----------------
__global__ __launch_bounds__(1024) void scan_kernel(
    const int* __restrict__ cnt, int* __restrict__ cellStart)
{
  __shared__ int s[2][2048];
  int t = threadIdx.x;
  s[0][t] = cnt[t];
  s[0][t + 1024] = cnt[t + 1024];
  __syncthreads();
  int src = 0;
  for (int off = 1; off < 2048; off <<= 1) {
    int dst = src ^ 1;
    for (int i = t; i < 2048; i += 1024) {
      int v = s[src][i];
      if (i >= off) v += s[src][i - off];
      s[dst][i] = v;
    }
    __syncthreads();
    src ^= 1;
  }
  cellStart[t] = (t == 0) ? 0 : s[src][t - 1];
  cellStart[t + 1024] = s[src][t + 1023];
}

// ---------------- scatter: counting-sort points by cell ----------------
__global__ __launch_bounds__(256) void scatter_kernel(
    const float* __restrict__ pos4, const int* __restrict__ cid16,
    const int* __restrict__ cellStart, int* __restrict__ cellOfs,
    float4* __restrict__ pos4s, int* __restrict__ sid)
{
  int i = blockIdx.x * 256 + threadIdx.x;
  int b = i >> 13;
  int cg = b * GC + cid16[i];
  int dst = cellStart[cg] + atomicAdd(&cellOfs[cg], 1);
  pos4s[dst] = *reinterpret_cast<const float4*>(pos4 + (size_t)i * 4);
  sid[dst] = i & (N - 1);
}

// ---------------- knn phase 1: wave-uniform box scan (64 sorted queries / wave) ----------------
// Wave scans the union bounding box of all lanes' 3x3x3 windows, rows filtered by ballot.
// Candidate addresses are wave-uniform -> scalar loads. Exactness certified per lane by
// own-window margin test; failures appended to failList for exact brute-force fallback.
__global__ __launch_bounds__(64) void knn_box_kernel(
    const float4* __restrict__ pos4s, const int* __restrict__ sid,
    const int* __restrict__ cellStart, int* __restrict__ knn,
    int* __restrict__ failList, int* __restrict__ nFail)
{
  __shared__ unsigned long long buf[BUFK * 64];
  int tid = threadIdx.x;
  int s = blockIdx.x * 64 + tid;
  int b = s >> 13;
  float4 q = pos4s[s];
  int myid = sid[s];
  int cx = cellco(q.x), cy = cellco(q.y), cz = cellco(q.z);

  // wave min/max of cell coords
  int mnx = cx, mxx = cx, mny = cy, mxy = cy, mnz = cz, mxz = cz;
  #pragma unroll
  for (int msk = 1; msk < 64; msk <<= 1) {
    mnx = min(mnx, __shfl_xor(mnx, msk)); mxx = max(mxx, __shfl_xor(mxx, msk));
    mny = min(mny, __shfl_xor(mny, msk)); mxy = max(mxy, __shfl_xor(mxy, msk));
    mnz = min(mnz, __shfl_xor(mnz, msk)); mxz = max(mxz, __shfl_xor(mxz, msk));
  }
  int bx0 = max(mnx - 1, 0), bx1 = min(mxx + 1, GRID - 1);
  int by0 = max(mny - 1, 0), by1 = min(mxy + 1, GRID - 1);
  int bz0 = max(mnz - 1, 0), bz1 = min(mxz + 1, GRID - 1);

  unsigned long long dk[16];
  #pragma unroll
  for (int j = 0; j < 16; ++j) dk[j] = 0x7F7FFFFF00000000ULL;  // FLT_MAX | 0
  float thr = 3.4e38f;
  int c = 0;

  auto merge = [&]() {
    #pragma unroll 1
    for (int t = 0; t < BUFK; ++t) {
      if (__all(t >= c)) break;
      unsigned long long key = ~0ULL;
      if (t < c) key = buf[(t << 6) + tid];
      if (key < dk[15]) {
        bool bj = true;
        #pragma unroll
        for (int j = 15; j >= 1; --j) {
          bool bjm1 = key < dk[j - 1];
          dk[j] = bj ? (bjm1 ? dk[j - 1] : key) : dk[j];
          bj = bjm1;
        }
        if (bj) dk[0] = key;
      }
    }
    c = 0;
    thr = __uint_as_float((unsigned)(dk[15] >> 32));
  };

  const int cbase = b * GC;
  #pragma unroll 1
  for (int zz = bz0; zz <= bz1; ++zz) {
    #pragma unroll 1
    for (int yy = by0; yy <= by1; ++yy) {
      // skip rows not in any lane's 3x3x3 window
      if (!__any((abs(zz - cz) <= 1) && (abs(yy - cy) <= 1))) continue;
      int rowc = cbase + (zz * GRID + yy) * GRID;
      int i0 = cellStart[rowc + bx0], i1 = cellStart[rowc + bx1 + 1];
      #pragma unroll 1
      for (int i = i0; i < i1; ++i) {
        float4 cp = pos4s[i];                      // wave-uniform -> s_load
        float inn = q.x * cp.x + q.y * cp.y + q.z * cp.z;
        float dist = fmaf(-2.f, inn, q.w + cp.w);
        if (dist < thr) {
          dist = fmaxf(dist, 0.f);
          buf[(c << 6) + tid] =
              ((unsigned long long)__float_as_uint(dist) << 32) | (unsigned)sid[i];
          ++c;
        }
        if (__any(c == BUFK)) merge();
      }
    }
  }
  merge();

  // margin certificate from own 3x3x3 window (domain faces -> infinite)
  float mx = 3.4e38f;
  if (cx > 1)        mx = fminf(mx, q.x - (cx - 1) * H);
  if (cx < GRID - 2) mx = fminf(mx, (cx + 2) * H - q.x);
  if (cy > 1)        mx = fminf(mx, q.y - (cy - 1) * H);
  if (cy < GRID - 2) mx = fminf(mx, (cy + 2) * H - q.y);
  if (cz > 1)        mx = fminf(mx, q.z - (cz - 1) * H);
  if (cz < GRID - 2) mx = fminf(mx, (cz + 2) * H - q.z);
  float d16 = __uint_as_float((unsigned)(dk[15] >> 32));
  if (!(d16 <= mx * mx * 0.9999f)) {
    int slot = atomicAdd(nFail, 1);
    failList[slot] = b * N + myid;
  }

  int* orow = knn + ((size_t)b * N + myid) * 16;
  #pragma unroll
  for (int j = 0; j < 16; ++j) orow[j] = (int)(dk[j] & 0xFFFFFFFFULL);
}

// ---------------- knn fallback: exact brute force, one wave per failed query ----------------
__global__ __launch_bounds__(64) void knn_fallback_kernel(
    const float4* __restrict__ pos4u, const float4* __restrict__ pos4s,
    const int* __restrict__ sid, const int* __restrict__ failList,
    const int* __restrict__ nFail, int* __restrict__ knn)
{
  int lane = threadIdx.x;
  int nf = nFail[0];
  #pragma unroll 1
  for (int w = blockIdx.x; w < nf; w += gridDim.x) {
    int g = failList[w];
    int b = g >> 13;
    float4 q = pos4u[g];
    unsigned long long dk[16];
    #pragma unroll
    for (int j = 0; j < 16; ++j) dk[j] = ~0ULL;
    int base = b * N;
    #pragma unroll 1
    for (int i = lane; i < N; i += 64) {
      float4 cp = pos4s[base + i];                 // coalesced per-lane
      float inn = q.x * cp.x + q.y * cp.y + q.z * cp.z;
      float dist = fmaf(-2.f, inn, q.w + cp.w);
      dist = fmaxf(dist, 0.f);
      unsigned long long key =
          ((unsigned long long)__float_as_uint(dist) << 32) | (unsigned)sid[base + i];
      if (key < dk[15]) {
        bool bj = true;
        #pragma unroll
        for (int j = 15; j >= 1; --j) {
          bool bjm1 = key < dk[j - 1];
          dk[j] = bj ? (bjm1 ? dk[j - 1] : key) : dk[j];
          bj = bjm1;
        }
        if (bj) dk[0] = key;
      }
    }
    // merge 64 sorted lists: 16 rounds of wave-min + winner shift
    int* orow = knn + (size_t)g * 16;
    #pragma unroll 1
    for (int r_ = 0; r_ < 16; ++r_) {
      unsigned long long m = dk[0];
      #pragma unroll
      for (int msk = 1; msk < 64; msk <<= 1) {
        unsigned long long o = __shfl_xor(m, msk);
        m = (o < m) ? o : m;
      }
      bool win = (dk[0] == m);                     // keys unique (contain idx)
      if (lane == 0) orow[r_] = (int)(m & 0xFFFFFFFFULL);
      if (win) {
        #pragma unroll
        for (int j = 0; j < 15; ++j) dk[j] = dk[j + 1];
        dk[15] = ~0ULL;
      }
    }
  }
}

// ---------------- qkv (MFMA): X = lrelu(bn(W1@feats)); q/k/v = W@X stored bf16 [pt][64] ----------------
__global__ __launch_bounds__(256) void qkv_kernel(
    const float* __restrict__ feats, const int4* __restrict__ AF,
    const float* __restrict__ b1p,
    uint2* __restrict__ qT, uint2* __restrict__ kT, uint2* __restrict__ vT)
{
  __shared__ int4 sA[2048];   // W1 | Wq | Wk | Wv
  for (int i = threadIdx.x; i < 2048; i += 256) sA[i] = AF[i];
  __syncthreads();
  int lane = threadIdx.x & 63, w = threadIdx.x >> 6;
  int gw = blockIdx.x * 4 + w;
  int col = lane & 31, h = lane >> 5;
  int nb = gw * 32;
  int b = nb >> 13;
  int n = (nb & (N - 1)) + col;
  size_t gpt = (size_t)b * N + n;
  const float* fb = feats + (size_t)b * D * N + n;

  Frag Bf[4];
  #pragma unroll
  for (int t = 0; t < 4; ++t) {
    int c0 = 16 * t + 8 * h;
    float f[8];
    #pragma unroll
    for (int i = 0; i < 8; ++i) f[i] = fb[(size_t)(c0 + i) * N];
    #pragma unroll
    for (int d_ = 0; d_ < 4; ++d_) Bf[t].u[d_] = pk2(f[2*d_], f[2*d_+1]);
  }
  f32x16 acc0 = {}, acc1 = {};
  #pragma unroll
  for (int t = 0; t < 4; ++t) {
    acc0 = MF(sA[t * 64 + lane], Bf[t], acc0);
    acc1 = MF(sA[(4 + t) * 64 + lane], Bf[t], acc1);
  }
  const float4* bp = (const float4*)b1p;
  f32x16 x0 = biasAct(acc0, bp, 0, h);
  f32x16 x1 = biasAct(acc1, bp, 1, h);
  Frag Bx[4];
  buildB(x0, x1, h, Bx);

  #pragma unroll
  for (int mmat = 0; mmat < 3; ++mmat) {
    const int4* Am = sA + 512 * (mmat + 1);
    uint2* op = (mmat == 0) ? qT : (mmat == 1) ? kT : vT;
    f32x16 a0 = {}, a1 = {};
    #pragma unroll
    for (int t = 0; t < 4; ++t) {
      a0 = MF(Am[t * 64 + lane], Bx[t], a0);
      a1 = MF(Am[(4 + t) * 64 + lane], Bx[t], a1);
    }
    #pragma unroll
    for (int q = 0; q < 4; ++q) {
      uint2 v0, v1;
      v0.x = pk2(a0[4*q+0], a0[4*q+1]); v0.y = pk2(a0[4*q+2], a0[4*q+3]);
      v1.x = pk2(a1[4*q+0], a1[4*q+1]); v1.y = pk2(a1[4*q+2], a1[4*q+3]);
      op[gpt * 16 + 2 * q + h] = v0;
      op[gpt * 16 + 8 + 2 * q + h] = v1;
    }
  }
}

// ---------------- fused (MFMA): pe -> pos_enc -> a0 -> a1 -> a2 -> softmax -> res ----------------
__global__ __launch_bounds__(256) void fused_kernel(
    const float4* __restrict__ pos4, const int* __restrict__ knn,
    const uint2* __restrict__ qT, const uint2* __restrict__ kT, const uint2* __restrict__ vT,
    const int4* __restrict__ AF,      // [Wd2 | Wg1 | Wg2 | Wd1]
    const float* __restrict__ biases, // bd2p | bg1p | bg2p
    float* __restrict__ res_ws)
{
  __shared__ int4 sA[1664];
  for (int i = threadIdx.x; i < 1664; i += 256) sA[i] = AF[i];
  __syncthreads();
  const float4* bpd2 = (const float4*)(biases);
  const float4* bpg1 = (const float4*)(biases + 64);
  const float4* bpg2 = (const float4*)(biases + 128);

  int lane = threadIdx.x & 63, w = threadIdx.x >> 6;
  int gw = blockIdx.x * 4 + w;
  int col = lane & 31, h = lane >> 5;
  int p = col >> 4, kk = col & 15;
  int pbase = gw * 2;
  int b = pbase >> 13;
  int n = (pbase & (N - 1)) + p;
  size_t g = (size_t)b * N + n;
  int m = knn[g * 16 + kk];
  size_t gm = (size_t)b * N + m;

  float4 P = pos4[g], Q = pos4[gm];
  float rx = P.x - Q.x, ry = P.y - Q.y, rz = P.z - Q.z;

  // L0: pe = lrelu(s*Wd1@rel + bd1)   (bias via B k=3 column)
  Frag B0;
  B0.u[0] = h ? 0u : pk2(rx, ry);
  B0.u[1] = h ? 0u : pk2(rz, 1.0f);
  B0.u[2] = 0u; B0.u[3] = 0u;
  f32x16 acc0 = {}, acc1 = {};
  acc0 = MF(sA[1536 + lane], B0, acc0);
  acc1 = MF(sA[1536 + 64 + lane], B0, acc1);
  f32x16 pe0, pe1;
  #pragma unroll
  for (int i = 0; i < 16; ++i) { pe0[i] = lrelu(acc0[i]); pe1[i] = lrelu(acc1[i]); }
  Frag Bp[4];
  buildB(pe0, pe1, h, Bp);

  // L1: pos_enc = lrelu(s*Wd2@pe + bd2)
  acc0 = (f32x16){}; acc1 = (f32x16){};
  #pragma unroll
  for (int t = 0; t < 4; ++t) {
    acc0 = MF(sA[t * 64 + lane], Bp[t], acc0);
    acc1 = MF(sA[(4 + t) * 64 + lane], Bp[t], acc1);
  }
  f32x16 pn0 = biasAct(acc0, bpd2, 0, h);
  f32x16 pn1 = biasAct(acc1, bpd2, 1, h);

  unsigned pep[8][2];
  #pragma unroll
  for (int q = 0; q < 4; ++q) {
    pep[q][0]   = pk2(pn0[4*q+0], pn0[4*q+1]);
    pep[q][1]   = pk2(pn0[4*q+2], pn0[4*q+3]);
    pep[4+q][0] = pk2(pn1[4*q+0], pn1[4*q+1]);
    pep[4+q][1] = pk2(pn1[4*q+2], pn1[4*q+3]);
  }

  // a0 = q[n] - k[m] + pos_enc
  f32x16 av0, av1;
  #pragma unroll
  for (int mt = 0; mt < 2; ++mt) {
    f32x16& dst = mt ? av1 : av0;
    const f32x16& pn = mt ? pn1 : pn0;
    #pragma unroll
    for (int q = 0; q < 4; ++q) {
      uint2 qv = qT[g * 16 + 8 * mt + 2 * q + h];
      uint2 kv = kT[gm * 16 + 8 * mt + 2 * q + h];
      dst[4*q+0] = pn[4*q+0] + blo(qv.x) - blo(kv.x);
      dst[4*q+1] = pn[4*q+1] + bhi(qv.x) - bhi(kv.x);
      dst[4*q+2] = pn[4*q+2] + blo(qv.y) - blo(kv.y);
      dst[4*q+3] = pn[4*q+3] + bhi(qv.y) - bhi(kv.y);
    }
  }
  buildB(av0, av1, h, Bp);

  // L2: a1 = lrelu(s*Wg1@a0 + bg1)
  acc0 = (f32x16){}; acc1 = (f32x16){};
  #pragma unroll
  for (int t = 0; t < 4; ++t) {
    acc0 = MF(sA[512 + t * 64 + lane], Bp[t], acc0);
    acc1 = MF(sA[512 + (4 + t) * 64 + lane], Bp[t], acc1);
  }
  f32x16 a10 = biasAct(acc0, bpg1, 0, h);
  f32x16 a11 = biasAct(acc1, bpg1, 1, h);
  buildB(a10, a11, h, Bp);

  // L3: a2 = lrelu(s*Wg2@a1 + bg2) * RSQN
  acc0 = (f32x16){}; acc1 = (f32x16){};
  #pragma unroll
  for (int t = 0; t < 4; ++t) {
    acc0 = MF(sA[1024 + t * 64 + lane], Bp[t], acc0);
    acc1 = MF(sA[1024 + (4 + t) * 64 + lane], Bp[t], acc1);
  }
  f32x16 at0 = biasAct(acc0, bpg2, 0, h);
  f32x16 at1 = biasAct(acc1, bpg2, 1, h);
  #pragma unroll
  for (int i = 0; i < 16; ++i) { at0[i] *= RSQN; at1[i] *= RSQN; }

  // softmax over kk + weighted sum of vpe = v + pos_enc
  float* rp = res_ws + g * 64;
  #pragma unroll
  for (int mt = 0; mt < 2; ++mt) {
    const f32x16& at = mt ? at1 : at0;
    f32x16 ev, nm;
    #pragma unroll
    for (int q = 0; q < 4; ++q) {
      uint2 vv = vT[gm * 16 + 8 * mt + 2 * q + h];
      unsigned pp0 = pep[mt * 4 + q][0], pp1 = pep[mt * 4 + q][1];
      float vp0 = blo(vv.x) + blo(pp0);
      float vp1 = bhi(vv.x) + bhi(pp0);
      float vp2 = blo(vv.y) + blo(pp1);
      float vp3 = bhi(vv.y) + bhi(pp1);
      ev[4*q+0] = __expf(at[4*q+0]); nm[4*q+0] = ev[4*q+0] * vp0;
      ev[4*q+1] = __expf(at[4*q+1]); nm[4*q+1] = ev[4*q+1] * vp1;
      ev[4*q+2] = __expf(at[4*q+2]); nm[4*q+2] = ev[4*q+2] * vp2;
      ev[4*q+3] = __expf(at[4*q+3]); nm[4*q+3] = ev[4*q+3] * vp3;
    }
    #pragma unroll
    for (int i = 0; i < 16; ++i) {
      #pragma unroll
      for (int mask = 1; mask <= 8; mask <<= 1) {
        ev[i] += __shfl_xor(ev[i], mask);
        nm[i] += __shfl_xor(nm[i], mask);
      }
    }
    if (kk == 0) {
      #pragma unroll
      for (int q = 0; q < 4; ++q) {
        float4 r;
        r.x = nm[4*q+0] / ev[4*q+0];
        r.y = nm[4*q+1] / ev[4*q+1];
        r.z = nm[4*q+2] / ev[4*q+2];
        r.w = nm[4*q+3] / ev[4*q+3];
        *(float4*)(rp + 32 * mt + 8 * q + 4 * h) = r;
      }
    }
  }
}

// ---------------- final (MFMA): out = lrelu(bn(W2@res)) + feats ----------------
__global__ __launch_bounds__(256) void final_kernel(
    const float* __restrict__ res_ws, const int4* __restrict__ AF,
    const float* __restrict__ b2p, const float* __restrict__ feats,
    float* __restrict__ out)
{
  __shared__ int4 sA[512];
  for (int i = threadIdx.x; i < 512; i += 256) sA[i] = AF[i];
  __syncthreads();
  int lane = threadIdx.x & 63, w = threadIdx.x >> 6;
  int gw = blockIdx.x * 4 + w;
  int col = lane & 31, h = lane >> 5;
  int nb = gw * 32;
  int b = nb >> 13;
  int n = (nb & (N - 1)) + col;
  size_t g = (size_t)b * N + n;
  const float* rp = res_ws + g * 64;
  Frag Br[4];
  #pragma unroll
  for (int t = 0; t < 4; ++t) {
    float4 r0 = *(const float4*)(rp + 16 * t + 8 * h);
    float4 r1 = *(const float4*)(rp + 16 * t + 8 * h + 4);
    Br[t].u[0] = pk2(r0.x, r0.y); Br[t].u[1] = pk2(r0.z, r0.w);
    Br[t].u[2] = pk2(r1.x, r1.y); Br[t].u[3] = pk2(r1.z, r1.w);
  }
  f32x16 a0 = {}, a1 = {};
  #pragma unroll
  for (int t = 0; t < 4; ++t) {
    a0 = MF(sA[t * 64 + lane], Br[t], a0);
    a1 = MF(sA[(4 + t) * 64 + lane], Br[t], a1);
  }
  const float4* bp = (const float4*)b2p;
  f32x16 o0 = biasAct(a0, bp, 0, h);
  f32x16 o1 = biasAct(a1, bp, 1, h);
  const float* fb = feats + (size_t)b * D * N;
  float* ob = out + (size_t)b * D * N;
  #pragma unroll
  for (int mt = 0; mt < 2; ++mt) {
    const f32x16& oo = mt ? o1 : o0;
    #pragma unroll
    for (int q = 0; q < 4; ++q) {
      #pragma unroll
      for (int j = 0; j < 4; ++j) {
        int chan = 32 * mt + 8 * q + 4 * h + j;
        ob[(size_t)chan * N + n] = oo[4*q+j] + fb[(size_t)chan * N + n];
      }
    }
  }
}

} // namespace

extern "C" void kernel_launch(void* const* d_in, const int* in_sizes, int n_in,
                              void* d_out, int out_size, void* d_ws, size_t ws_size,
                              hipStream_t stream) {
  const float* feats = (const float*)d_in[0];
  const float* pos   = (const float*)d_in[1];
  const float* W1  = (const float*)d_in[3];
  const float* g1  = (const float*)d_in[4];
  const float* b1  = (const float*)d_in[5];
  const float* Wq  = (const float*)d_in[6];
  const float* Wk  = (const float*)d_in[7];
  const float* Wv  = (const float*)d_in[8];
  const float* Wd1 = (const float*)d_in[9];
  const float* gd1 = (const float*)d_in[10];
  const float* bd1 = (const float*)d_in[11];
  const float* Wd2 = (const float*)d_in[12];
  const float* gd2 = (const float*)d_in[13];
  const float* bd2 = (const float*)d_in[14];
  const float* Wg1 = (const float*)d_in[15];
  const float* gg1 = (const float*)d_in[16];
  const float* bg1 = (const float*)d_in[17];
  const float* Wg2 = (const float*)d_in[18];
  const float* gg2 = (const float*)d_in[19];
  const float* bg2 = (const float*)d_in[20];
  const float* W2  = (const float*)d_in[21];
  const float* g2  = (const float*)d_in[22];
  const float* b2  = (const float*)d_in[23];

  uint8_t* wsb = (uint8_t*)d_ws;
  unsigned short* AF = (unsigned short*)wsb;               // bf16 A-frags (73728 B reserved)
  float* biasAll = (float*)(wsb + 73728);                  // 320 floats
  float* pos4    = (float*)(wsb + 75008);                  // 65536 floats (256 KB)
  uint2* qTb     = (uint2*)(wsb + 337152);                 // 2 MB
  uint2* kTb     = (uint2*)(wsb + 2434304);                // 2 MB
  uint2* vTb     = (uint2*)(wsb + 4531456);                // 2 MB
  float* res_ws  = (float*)(wsb + 6628608);                // 4 MB
  int*   cid16     = (int*)(wsb + 10822912);               // 64 KB
  int*   cellCount = (int*)(wsb + 10888448);               // 8 KB (2048)
  int*   cellStart = (int*)(wsb + 10896640);               // 8 KB (2048+1)
  int*   cellOfs   = (int*)(wsb + 10904832);               // 8 KB (2048)
  float4* pos4s    = (float4*)(wsb + 10913024);            // 256 KB
  int*   sid       = (int*)(wsb + 11175168);               // 64 KB
  int*   knn       = (int*)(wsb + 11240704);               // 1 MB (16384*16*4)
  int*   failList  = (int*)(wsb + 12289280);               // 64 KB
  int*   nFail     = (int*)(wsb + 12355072);               // 4 B

  PrepArgs pa;
  pa.W[0] = W1;  pa.W[1] = Wq;  pa.W[2] = Wk;  pa.W[3] = Wv;
  pa.W[4] = Wd2; pa.W[5] = Wg1; pa.W[6] = Wg2; pa.W[7] = W2; pa.W[8] = Wd1;
  pa.scale[0] = g1;  pa.scale[1] = nullptr; pa.scale[2] = nullptr; pa.scale[3] = nullptr;
  pa.scale[4] = gd2; pa.scale[5] = gg1;     pa.scale[6] = gg2;     pa.scale[7] = g2; pa.scale[8] = gd1;
  pa.bias[0] = b1; pa.bias[1] = bd2; pa.bias[2] = bg1; pa.bias[3] = bg2; pa.bias[4] = b2;
  pa.bd1 = bd1;

  hipMemsetAsync(cellCount, 0, 2048 * sizeof(int), stream);
  hipMemsetAsync(cellOfs, 0, 2048 * sizeof(int), stream);
  hipMemsetAsync(nFail, 0, sizeof(int), stream);
  hipLaunchKernelGGL(prep_kernel, dim3(9), dim3(256), 0, stream, pa, AF, biasAll);
  hipLaunchKernelGGL(pos4cid_kernel, dim3(B * N / 256), dim3(256), 0, stream,
                     pos, pos4, cid16, cellCount);
  hipLaunchKernelGGL(scan_kernel, dim3(1), dim3(1024), 0, stream, cellCount, cellStart);
  hipLaunchKernelGGL(scatter_kernel, dim3(B * N / 256), dim3(256), 0, stream,
                     pos4, cid16, cellStart, cellOfs, pos4s, sid);
  hipLaunchKernelGGL(qkv_kernel, dim3(128), dim3(256), 0, stream,
                     feats, (const int4*)wsb, biasAll, qTb, kTb, vTb);
  hipLaunchKernelGGL(knn_box_kernel, dim3(B * N / 64), dim3(64), 0, stream,
                     pos4s, sid, cellStart, knn, failList, nFail);
  hipLaunchKernelGGL(knn_fallback_kernel, dim3(1024), dim3(64), 0, stream,
                     (const float4*)pos4, pos4s, sid, failList, nFail, knn);
  hipLaunchKernelGGL(fused_kernel, dim3(2048), dim3(256), 0, stream,
                     (const float4*)pos4, knn, qTb, kTb, vTb,
                     (const int4*)(wsb + 32768), biasAll + 64, res_ws);
  hipLaunchKernelGGL(final_kernel, dim3(128), dim3(256), 0, stream,
                     res_ws, (const int4*)(wsb + 59392), biasAll + 256, feats, (float*)d_out);
}

// Round 6
// 179.242 us; speedup vs baseline: 2.7372x; 2.7372x over previous
//
#include <hip/hip_runtime.h>
#include <hip/hip_bf16.h>
#include <math.h>

namespace {

constexpr int B = 2;
constexpr int N = 8192;
constexpr int D = 64;
constexpr int GRID = 10;
constexpr int GC = GRID * GRID * GRID;     // 1000 cells per batch
constexpr float H = 0.1f;
constexpr float NEGS = 0.2f;
constexpr float BN_INV = 0.9999950000374997f;   // 1/sqrt(1+1e-5)
constexpr float RSQN = 0.011048543456039806f;   // 1/sqrt(8192)

typedef __attribute__((ext_vector_type(8))) short bf16x8;
typedef __attribute__((ext_vector_type(16))) float f32x16;

union Frag { int4 i4; unsigned u[4]; bf16x8 h; };

__device__ __forceinline__ float lrelu(float v) { return v > 0.f ? v : NEGS * v; }

__device__ __forceinline__ unsigned pk2(float a, float b) {
  __hip_bfloat162 h2 = __float22bfloat162_rn(make_float2(a, b));
  unsigned r;
  __builtin_memcpy(&r, &h2, 4);
  return r;
}
__device__ __forceinline__ float blo(unsigned u) { return __uint_as_float(u << 16); }
__device__ __forceinline__ float bhi(unsigned u) { return __uint_as_float(u & 0xFFFF0000u); }

__device__ __forceinline__ f32x16 MF(int4 a, const Frag& b, f32x16 c) {
  Frag af; af.i4 = a;
  return __builtin_amdgcn_mfma_f32_32x32x16_bf16(af.h, b.h, c, 0, 0, 0);
}

__device__ __forceinline__ int cellco(float v) {
  int c = (int)(v * 10.0f);
  return min(max(c, 0), GRID - 1);
}

// D-layout f32 (x0: chans 0-31 rows, x1: chans 32-63) -> B-fragments for next layer.
__device__ __forceinline__ void buildB(const f32x16& x0, const f32x16& x1, int h, Frag Bf[4]) {
  unsigned Z[8][2];
  #pragma unroll
  for (int q = 0; q < 4; ++q) {
    Z[q][0]     = pk2(x0[4*q+0], x0[4*q+1]);
    Z[q][1]     = pk2(x0[4*q+2], x0[4*q+3]);
    Z[4+q][0]   = pk2(x1[4*q+0], x1[4*q+1]);
    Z[4+q][1]   = pk2(x1[4*q+2], x1[4*q+3]);
  }
  unsigned S[8][2];
  #pragma unroll
  for (int q = 0; q < 8; ++q) {
    S[q][0] = (unsigned)__shfl_xor((int)Z[q][0], 32);
    S[q][1] = (unsigned)__shfl_xor((int)Z[q][1], 32);
  }
  #pragma unroll
  for (int t = 0; t < 4; ++t) {
    int qq = (t >> 1) * 4 + 2 * (t & 1);
    Bf[t].u[0] = h ? S[qq+1][0] : Z[qq][0];
    Bf[t].u[1] = h ? S[qq+1][1] : Z[qq][1];
    Bf[t].u[2] = h ? Z[qq+1][0] : S[qq][0];
    Bf[t].u[3] = h ? Z[qq+1][1] : S[qq][1];
  }
}

__device__ __forceinline__ f32x16 biasAct(f32x16 d, const float4* bp, int mt, int h) {
  f32x16 r;
  #pragma unroll
  for (int q = 0; q < 4; ++q) {
    float4 bb = bp[h * 8 + mt * 4 + q];
    r[4*q+0] = lrelu(d[4*q+0] + bb.x);
    r[4*q+1] = lrelu(d[4*q+1] + bb.y);
    r[4*q+2] = lrelu(d[4*q+2] + bb.z);
    r[4*q+3] = lrelu(d[4*q+3] + bb.w);
  }
  return r;
}

// ---------------- prep: pack A-fragments (bf16, BN scale folded) + permuted biases ----------------
struct PrepArgs {
  const float* W[9];       // W1,Wq,Wk,Wv,Wd2,Wg1,Wg2,W2,Wd1
  const float* scale[9];
  const float* bias[5];    // b1,bd2,bg1,bg2,b2
  const float* bd1;
};

__global__ __launch_bounds__(256) void prep_kernel(PrepArgs a, unsigned short* AF, float* biasAll) {
  int mi = blockIdx.x;
  int tid = threadIdx.x;
  if (mi < 8) {
    int off = (mi == 7) ? 29696 : mi * 4096;
    const float* W = a.W[mi];
    const float* G = a.scale[mi];
    unsigned short* dst = AF + off;
    for (int e = tid; e < 4096; e += 256) {
      int i = e & 7, lane = (e >> 3) & 63, t = (e >> 9) & 3, mt = e >> 11;
      int row = 32 * mt + (lane & 31);
      int k = 16 * t + 8 * (lane >> 5) + i;
      float v = W[row * 64 + k];
      if (G) v *= G[row] * BN_INV;
      __hip_bfloat16 hb = __float2bfloat16(v);
      __builtin_memcpy(&dst[e], &hb, 2);
    }
  } else {
    const float* W = a.W[8];
    const float* G = a.scale[8];
    for (int e = tid; e < 1024; e += 256) {
      int i = e & 7, lane = (e >> 3) & 63, mt = e >> 9;
      int row = 32 * mt + (lane & 31), h = lane >> 5;
      float v = 0.f;
      if (h == 0) {
        if (i < 3) v = W[row * 3 + i] * G[row] * BN_INV;
        else if (i == 3) v = a.bd1[row];
      }
      __hip_bfloat16 hb = __float2bfloat16(v);
      __builtin_memcpy(&AF[28672 + e], &hb, 2);
    }
    for (int e = tid; e < 320; e += 256) {
      int ai = e >> 6, idx = e & 63;
      int h = idx >> 5, mt = (idx >> 4) & 1, q = (idx >> 2) & 3, j = idx & 3;
      biasAll[e] = a.bias[ai][32 * mt + 8 * q + 4 * h + j];
    }
  }
}

// ---------------- pos4 + cell id + histogram ----------------
__global__ __launch_bounds__(256) void pos4cid_kernel(
    const float* __restrict__ pos, float* __restrict__ pos4,
    int* __restrict__ cid16, int* __restrict__ cellCount)
{
  int i = blockIdx.x * 256 + threadIdx.x;
  int b = i >> 13;
  int n = i & (N - 1);
  const float* pb = pos + (size_t)b * 3 * N;
  float x = pb[n], y = pb[N + n], z = pb[2 * N + n];
  float4 v = {x, y, z, x * x + y * y + z * z};
  *reinterpret_cast<float4*>(pos4 + (size_t)i * 4) = v;
  int cid = (cellco(z) * GRID + cellco(y)) * GRID + cellco(x);
  cid16[i] = cid;
  atomicAdd(&cellCount[b * GC + cid], 1);
}

// ---------------- scan: exclusive prefix over 2048 cell counts (single block) ----------------
__global__ __launch_bounds__(1024) void scan_kernel(
    const int* __restrict__ cnt, int* __restrict__ cellStart)
{
  __shared__ int s[2][2048];
  int t = threadIdx.x;
  s[0][t] = cnt[t];
  s[0][t + 1024] = cnt[t + 1024];
  __syncthreads();
  int src = 0;
  for (int off = 1; off < 2048; off <<= 1) {
    int dst = src ^ 1;
    for (int i = t; i < 2048; i += 1024) {
      int v = s[src][i];
      if (i >= off) v += s[src][i - off];
      s[dst][i] = v;
    }
    __syncthreads();
    src ^= 1;
  }
  cellStart[t] = (t == 0) ? 0 : s[src][t - 1];
  cellStart[t + 1024] = s[src][t + 1023];
}

// ---------------- scatter: counting-sort points by cell ----------------
__global__ __launch_bounds__(256) void scatter_kernel(
    const float* __restrict__ pos4, const int* __restrict__ cid16,
    const int* __restrict__ cellStart, int* __restrict__ cellOfs,
    float4* __restrict__ pos4s, int* __restrict__ sid)
{
  int i = blockIdx.x * 256 + threadIdx.x;
  int b = i >> 13;
  int cg = b * GC + cid16[i];
  int dst = cellStart[cg] + atomicAdd(&cellOfs[cg], 1);
  pos4s[dst] = *reinterpret_cast<const float4*>(pos4 + (size_t)i * 4);
  sid[dst] = i & (N - 1);
}

// ---------------- knn: one wave per query; shell expansion with margin certificate ----------------
// Lanes stride over the candidates of each (z,y) row of the (2r+1)^3 window (coalesced loads),
// keep per-lane sorted top-16 (u64 keys: dist|sid, exact reference tie-break), then 16 rounds
// of wave-min extraction. If the 16th distance exceeds the own-window margin (domain faces ->
// inf), rescan at r+1. Per-wave-uniform control flow; 16384 independent waves.
__global__ __launch_bounds__(256) void knn_shell_kernel(
    const float4* __restrict__ pos4s, const int* __restrict__ sid,
    const int* __restrict__ cellStart, int* __restrict__ knn)
{
  constexpr unsigned long long SENT = 0x7F7FFFFFFFFFFFFFULL;  // FLT_MAX | idx -1
  int wid = (blockIdx.x * 256 + threadIdx.x) >> 6;   // sorted slot = query
  int lane = threadIdx.x & 63;
  int b = wid >> 13;
  float4 q = pos4s[wid];
  int myid = sid[wid];
  int cx = cellco(q.x), cy = cellco(q.y), cz = cellco(q.z);
  const int cbase = b * GC;
  int* orow = knn + ((size_t)b * N + myid) * 16;

  #pragma unroll 1
  for (int r = 1; r < GRID; ++r) {
    unsigned long long dk[16];
    #pragma unroll
    for (int j = 0; j < 16; ++j) dk[j] = SENT;

    int x0 = max(cx - r, 0), x1 = min(cx + r, GRID - 1);
    int y0 = max(cy - r, 0), y1 = min(cy + r, GRID - 1);
    int z0 = max(cz - r, 0), z1 = min(cz + r, GRID - 1);
    #pragma unroll 1
    for (int zz = z0; zz <= z1; ++zz) {
      #pragma unroll 1
      for (int yy = y0; yy <= y1; ++yy) {
        int rowc = cbase + (zz * GRID + yy) * GRID;
        int i0 = cellStart[rowc + x0], i1 = cellStart[rowc + x1 + 1];
        #pragma unroll 1
        for (int i = i0 + lane; i < i1; i += 64) {
          float4 cp = pos4s[i];
          float inn = q.x * cp.x + q.y * cp.y + q.z * cp.z;
          float dist = fmaxf(fmaf(-2.f, inn, q.w + cp.w), 0.f);
          unsigned long long key =
              ((unsigned long long)__float_as_uint(dist) << 32) | (unsigned)sid[i];
          if (key < dk[15]) {
            bool bj = true;
            #pragma unroll
            for (int j = 15; j >= 1; --j) {
              bool bjm1 = key < dk[j - 1];
              dk[j] = bj ? (bjm1 ? dk[j - 1] : key) : dk[j];
              bj = bjm1;
            }
            if (bj) dk[0] = key;
          }
        }
      }
    }

    // extract wave top-16 (merge 64 sorted lists), write as we go
    float dlast = 0.f;
    #pragma unroll 1
    for (int e = 0; e < 16; ++e) {
      unsigned long long m = dk[0];
      #pragma unroll
      for (int msk = 1; msk < 64; msk <<= 1) {
        unsigned long long o = __shfl_xor(m, msk);
        m = (o < m) ? o : m;
      }
      if (dk[0] == m) {                      // unique winner (keys embed unique sid)
        #pragma unroll
        for (int j = 0; j < 15; ++j) dk[j] = dk[j + 1];
        dk[15] = SENT;
      }
      if (lane == 0) orow[e] = (int)(m & 0xFFFFFFFFULL);
      dlast = __uint_as_float((unsigned)(m >> 32));
    }

    // margin certificate from searched window (domain faces -> inf; inf*inf=inf is correct)
    float mg = 3.4e38f;
    if (cx - r > 0)        mg = fminf(mg, q.x - (cx - r) * H);
    if (cx + r < GRID - 1) mg = fminf(mg, (cx + r + 1) * H - q.x);
    if (cy - r > 0)        mg = fminf(mg, q.y - (cy - r) * H);
    if (cy + r < GRID - 1) mg = fminf(mg, (cy + r + 1) * H - q.y);
    if (cz - r > 0)        mg = fminf(mg, q.z - (cz - r) * H);
    if (cz + r < GRID - 1) mg = fminf(mg, (cz + r + 1) * H - q.z);
    if (dlast <= mg * mg * 0.999f) break;    // wave-uniform
  }
}

// ---------------- qkv (MFMA): X = lrelu(bn(W1@feats)); q/k/v = W@X stored bf16 [pt][64] ----------------
__global__ __launch_bounds__(256) void qkv_kernel(
    const float* __restrict__ feats, const int4* __restrict__ AF,
    const float* __restrict__ b1p,
    uint2* __restrict__ qT, uint2* __restrict__ kT, uint2* __restrict__ vT)
{
  __shared__ int4 sA[2048];   // W1 | Wq | Wk | Wv
  for (int i = threadIdx.x; i < 2048; i += 256) sA[i] = AF[i];
  __syncthreads();
  int lane = threadIdx.x & 63, w = threadIdx.x >> 6;
  int gw = blockIdx.x * 4 + w;
  int col = lane & 31, h = lane >> 5;
  int nb = gw * 32;
  int b = nb >> 13;
  int n = (nb & (N - 1)) + col;
  size_t gpt = (size_t)b * N + n;
  const float* fb = feats + (size_t)b * D * N + n;

  Frag Bf[4];
  #pragma unroll
  for (int t = 0; t < 4; ++t) {
    int c0 = 16 * t + 8 * h;
    float f[8];
    #pragma unroll
    for (int i = 0; i < 8; ++i) f[i] = fb[(size_t)(c0 + i) * N];
    #pragma unroll
    for (int d_ = 0; d_ < 4; ++d_) Bf[t].u[d_] = pk2(f[2*d_], f[2*d_+1]);
  }
  f32x16 acc0 = {}, acc1 = {};
  #pragma unroll
  for (int t = 0; t < 4; ++t) {
    acc0 = MF(sA[t * 64 + lane], Bf[t], acc0);
    acc1 = MF(sA[(4 + t) * 64 + lane], Bf[t], acc1);
  }
  const float4* bp = (const float4*)b1p;
  f32x16 x0 = biasAct(acc0, bp, 0, h);
  f32x16 x1 = biasAct(acc1, bp, 1, h);
  Frag Bx[4];
  buildB(x0, x1, h, Bx);

  #pragma unroll
  for (int mmat = 0; mmat < 3; ++mmat) {
    const int4* Am = sA + 512 * (mmat + 1);
    uint2* op = (mmat == 0) ? qT : (mmat == 1) ? kT : vT;
    f32x16 a0 = {}, a1 = {};
    #pragma unroll
    for (int t = 0; t < 4; ++t) {
      a0 = MF(Am[t * 64 + lane], Bx[t], a0);
      a1 = MF(Am[(4 + t) * 64 + lane], Bx[t], a1);
    }
    #pragma unroll
    for (int q = 0; q < 4; ++q) {
      uint2 v0, v1;
      v0.x = pk2(a0[4*q+0], a0[4*q+1]); v0.y = pk2(a0[4*q+2], a0[4*q+3]);
      v1.x = pk2(a1[4*q+0], a1[4*q+1]); v1.y = pk2(a1[4*q+2], a1[4*q+3]);
      op[gpt * 16 + 2 * q + h] = v0;
      op[gpt * 16 + 8 + 2 * q + h] = v1;
    }
  }
}

// ---------------- fused (MFMA): pe -> pos_enc -> a0 -> a1 -> a2 -> softmax -> res ----------------
__global__ __launch_bounds__(256) void fused_kernel(
    const float4* __restrict__ pos4, const int* __restrict__ knn,
    const uint2* __restrict__ qT, const uint2* __restrict__ kT, const uint2* __restrict__ vT,
    const int4* __restrict__ AF,      // [Wd2 | Wg1 | Wg2 | Wd1]
    const float* __restrict__ biases, // bd2p | bg1p | bg2p
    float* __restrict__ res_ws)
{
  __shared__ int4 sA[1664];
  for (int i = threadIdx.x; i < 1664; i += 256) sA[i] = AF[i];
  __syncthreads();
  const float4* bpd2 = (const float4*)(biases);
  const float4* bpg1 = (const float4*)(biases + 64);
  const float4* bpg2 = (const float4*)(biases + 128);

  int lane = threadIdx.x & 63, w = threadIdx.x >> 6;
  int gw = blockIdx.x * 4 + w;
  int col = lane & 31, h = lane >> 5;
  int p = col >> 4, kk = col & 15;
  int pbase = gw * 2;
  int b = pbase >> 13;
  int n = (pbase & (N - 1)) + p;
  size_t g = (size_t)b * N + n;
  int m = knn[g * 16 + kk];
  size_t gm = (size_t)b * N + m;

  float4 P = pos4[g], Q = pos4[gm];
  float rx = P.x - Q.x, ry = P.y - Q.y, rz = P.z - Q.z;

  // L0: pe = lrelu(s*Wd1@rel + bd1)   (bias via B k=3 column)
  Frag B0;
  B0.u[0] = h ? 0u : pk2(rx, ry);
  B0.u[1] = h ? 0u : pk2(rz, 1.0f);
  B0.u[2] = 0u; B0.u[3] = 0u;
  f32x16 acc0 = {}, acc1 = {};
  acc0 = MF(sA[1536 + lane], B0, acc0);
  acc1 = MF(sA[1536 + 64 + lane], B0, acc1);
  f32x16 pe0, pe1;
  #pragma unroll
  for (int i = 0; i < 16; ++i) { pe0[i] = lrelu(acc0[i]); pe1[i] = lrelu(acc1[i]); }
  Frag Bp[4];
  buildB(pe0, pe1, h, Bp);

  // L1: pos_enc = lrelu(s*Wd2@pe + bd2)
  acc0 = (f32x16){}; acc1 = (f32x16){};
  #pragma unroll
  for (int t = 0; t < 4; ++t) {
    acc0 = MF(sA[t * 64 + lane], Bp[t], acc0);
    acc1 = MF(sA[(4 + t) * 64 + lane], Bp[t], acc1);
  }
  f32x16 pn0 = biasAct(acc0, bpd2, 0, h);
  f32x16 pn1 = biasAct(acc1, bpd2, 1, h);

  unsigned pep[8][2];
  #pragma unroll
  for (int q = 0; q < 4; ++q) {
    pep[q][0]   = pk2(pn0[4*q+0], pn0[4*q+1]);
    pep[q][1]   = pk2(pn0[4*q+2], pn0[4*q+3]);
    pep[4+q][0] = pk2(pn1[4*q+0], pn1[4*q+1]);
    pep[4+q][1] = pk2(pn1[4*q+2], pn1[4*q+3]);
  }

  // a0 = q[n] - k[m] + pos_enc
  f32x16 av0, av1;
  #pragma unroll
  for (int mt = 0; mt < 2; ++mt) {
    f32x16& dst = mt ? av1 : av0;
    const f32x16& pn = mt ? pn1 : pn0;
    #pragma unroll
    for (int q = 0; q < 4; ++q) {
      uint2 qv = qT[g * 16 + 8 * mt + 2 * q + h];
      uint2 kv = kT[gm * 16 + 8 * mt + 2 * q + h];
      dst[4*q+0] = pn[4*q+0] + blo(qv.x) - blo(kv.x);
      dst[4*q+1] = pn[4*q+1] + bhi(qv.x) - bhi(kv.x);
      dst[4*q+2] = pn[4*q+2] + blo(qv.y) - blo(kv.y);
      dst[4*q+3] = pn[4*q+3] + bhi(qv.y) - bhi(kv.y);
    }
  }
  buildB(av0, av1, h, Bp);

  // L2: a1 = lrelu(s*Wg1@a0 + bg1)
  acc0 = (f32x16){}; acc1 = (f32x16){};
  #pragma unroll
  for (int t = 0; t < 4; ++t) {
    acc0 = MF(sA[512 + t * 64 + lane], Bp[t], acc0);
    acc1 = MF(sA[512 + (4 + t) * 64 + lane], Bp[t], acc1);
  }
  f32x16 a10 = biasAct(acc0, bpg1, 0, h);
  f32x16 a11 = biasAct(acc1, bpg1, 1, h);
  buildB(a10, a11, h, Bp);

  // L3: a2 = lrelu(s*Wg2@a1 + bg2) * RSQN
  acc0 = (f32x16){}; acc1 = (f32x16){};
  #pragma unroll
  for (int t = 0; t < 4; ++t) {
    acc0 = MF(sA[1024 + t * 64 + lane], Bp[t], acc0);
    acc1 = MF(sA[1024 + (4 + t) * 64 + lane], Bp[t], acc1);
  }
  f32x16 at0 = biasAct(acc0, bpg2, 0, h);
  f32x16 at1 = biasAct(acc1, bpg2, 1, h);
  #pragma unroll
  for (int i = 0; i < 16; ++i) { at0[i] *= RSQN; at1[i] *= RSQN; }

  // softmax over kk + weighted sum of vpe = v + pos_enc
  float* rp = res_ws + g * 64;
  #pragma unroll
  for (int mt = 0; mt < 2; ++mt) {
    const f32x16& at = mt ? at1 : at0;
    f32x16 ev, nm;
    #pragma unroll
    for (int q = 0; q < 4; ++q) {
      uint2 vv = vT[gm * 16 + 8 * mt + 2 * q + h];
      unsigned pp0 = pep[mt * 4 + q][0], pp1 = pep[mt * 4 + q][1];
      float vp0 = blo(vv.x) + blo(pp0);
      float vp1 = bhi(vv.x) + bhi(pp0);
      float vp2 = blo(vv.y) + blo(pp1);
      float vp3 = bhi(vv.y) + bhi(pp1);
      ev[4*q+0] = __expf(at[4*q+0]); nm[4*q+0] = ev[4*q+0] * vp0;
      ev[4*q+1] = __expf(at[4*q+1]); nm[4*q+1] = ev[4*q+1] * vp1;
      ev[4*q+2] = __expf(at[4*q+2]); nm[4*q+2] = ev[4*q+2] * vp2;
      ev[4*q+3] = __expf(at[4*q+3]); nm[4*q+3] = ev[4*q+3] * vp3;
    }
    #pragma unroll
    for (int i = 0; i < 16; ++i) {
      #pragma unroll
      for (int mask = 1; mask <= 8; mask <<= 1) {
        ev[i] += __shfl_xor(ev[i], mask);
        nm[i] += __shfl_xor(nm[i], mask);
      }
    }
    if (kk == 0) {
      #pragma unroll
      for (int q = 0; q < 4; ++q) {
        float4 r;
        r.x = nm[4*q+0] / ev[4*q+0];
        r.y = nm[4*q+1] / ev[4*q+1];
        r.z = nm[4*q+2] / ev[4*q+2];
        r.w = nm[4*q+3] / ev[4*q+3];
        *(float4*)(rp + 32 * mt + 8 * q + 4 * h) = r;
      }
    }
  }
}

// ---------------- final (MFMA): out = lrelu(bn(W2@res)) + feats ----------------
__global__ __launch_bounds__(256) void final_kernel(
    const float* __restrict__ res_ws, const int4* __restrict__ AF,
    const float* __restrict__ b2p, const float* __restrict__ feats,
    float* __restrict__ out)
{
  __shared__ int4 sA[512];
  for (int i = threadIdx.x; i < 512; i += 256) sA[i] = AF[i];
  __syncthreads();
  int lane = threadIdx.x & 63, w = threadIdx.x >> 6;
  int gw = blockIdx.x * 4 + w;
  int col = lane & 31, h = lane >> 5;
  int nb = gw * 32;
  int b = nb >> 13;
  int n = (nb & (N - 1)) + col;
  size_t g = (size_t)b * N + n;
  const float* rp = res_ws + g * 64;
  Frag Br[4];
  #pragma unroll
  for (int t = 0; t < 4; ++t) {
    float4 r0 = *(const float4*)(rp + 16 * t + 8 * h);
    float4 r1 = *(const float4*)(rp + 16 * t + 8 * h + 4);
    Br[t].u[0] = pk2(r0.x, r0.y); Br[t].u[1] = pk2(r0.z, r0.w);
    Br[t].u[2] = pk2(r1.x, r1.y); Br[t].u[3] = pk2(r1.z, r1.w);
  }
  f32x16 a0 = {}, a1 = {};
  #pragma unroll
  for (int t = 0; t < 4; ++t) {
    a0 = MF(sA[t * 64 + lane], Br[t], a0);
    a1 = MF(sA[(4 + t) * 64 + lane], Br[t], a1);
  }
  const float4* bp = (const float4*)b2p;
  f32x16 o0 = biasAct(a0, bp, 0, h);
  f32x16 o1 = biasAct(a1, bp, 1, h);
  const float* fb = feats + (size_t)b * D * N;
  float* ob = out + (size_t)b * D * N;
  #pragma unroll
  for (int mt = 0; mt < 2; ++mt) {
    const f32x16& oo = mt ? o1 : o0;
    #pragma unroll
    for (int q = 0; q < 4; ++q) {
      #pragma unroll
      for (int j = 0; j < 4; ++j) {
        int chan = 32 * mt + 8 * q + 4 * h + j;
        ob[(size_t)chan * N + n] = oo[4*q+j] + fb[(size_t)chan * N + n];
      }
    }
  }
}

} // namespace

extern "C" void kernel_launch(void* const* d_in, const int* in_sizes, int n_in,
                              void* d_out, int out_size, void* d_ws, size_t ws_size,
                              hipStream_t stream) {
  const float* feats = (const float*)d_in[0];
  const float* pos   = (const float*)d_in[1];
  const float* W1  = (const float*)d_in[3];
  const float* g1  = (const float*)d_in[4];
  const float* b1  = (const float*)d_in[5];
  const float* Wq  = (const float*)d_in[6];
  const float* Wk  = (const float*)d_in[7];
  const float* Wv  = (const float*)d_in[8];
  const float* Wd1 = (const float*)d_in[9];
  const float* gd1 = (const float*)d_in[10];
  const float* bd1 = (const float*)d_in[11];
  const float* Wd2 = (const float*)d_in[12];
  const float* gd2 = (const float*)d_in[13];
  const float* bd2 = (const float*)d_in[14];
  const float* Wg1 = (const float*)d_in[15];
  const float* gg1 = (const float*)d_in[16];
  const float* bg1 = (const float*)d_in[17];
  const float* Wg2 = (const float*)d_in[18];
  const float* gg2 = (const float*)d_in[19];
  const float* bg2 = (const float*)d_in[20];
  const float* W2  = (const float*)d_in[21];
  const float* g2  = (const float*)d_in[22];
  const float* b2  = (const float*)d_in[23];

  uint8_t* wsb = (uint8_t*)d_ws;
  unsigned short* AF = (unsigned short*)wsb;               // bf16 A-frags (73728 B reserved)
  float* biasAll = (float*)(wsb + 73728);                  // 320 floats
  float* pos4    = (float*)(wsb + 75008);                  // 65536 floats (256 KB)
  uint2* qTb     = (uint2*)(wsb + 337152);                 // 2 MB
  uint2* kTb     = (uint2*)(wsb + 2434304);                // 2 MB
  uint2* vTb     = (uint2*)(wsb + 4531456);                // 2 MB
  float* res_ws  = (float*)(wsb + 6628608);                // 4 MB
  int*   cid16     = (int*)(wsb + 10822912);               // 64 KB
  int*   cellCount = (int*)(wsb + 10888448);               // 8 KB (2048)
  int*   cellStart = (int*)(wsb + 10896640);               // 8 KB (2048+1)
  int*   cellOfs   = (int*)(wsb + 10904832);               // 8 KB (2048)
  float4* pos4s    = (float4*)(wsb + 10913024);            // 256 KB
  int*   sid       = (int*)(wsb + 11175168);               // 64 KB
  int*   knn       = (int*)(wsb + 11240704);               // 1 MB (16384*16*4)

  PrepArgs pa;
  pa.W[0] = W1;  pa.W[1] = Wq;  pa.W[2] = Wk;  pa.W[3] = Wv;
  pa.W[4] = Wd2; pa.W[5] = Wg1; pa.W[6] = Wg2; pa.W[7] = W2; pa.W[8] = Wd1;
  pa.scale[0] = g1;  pa.scale[1] = nullptr; pa.scale[2] = nullptr; pa.scale[3] = nullptr;
  pa.scale[4] = gd2; pa.scale[5] = gg1;     pa.scale[6] = gg2;     pa.scale[7] = g2; pa.scale[8] = gd1;
  pa.bias[0] = b1; pa.bias[1] = bd2; pa.bias[2] = bg1; pa.bias[3] = bg2; pa.bias[4] = b2;
  pa.bd1 = bd1;

  hipMemsetAsync(cellCount, 0, 2048 * sizeof(int), stream);
  hipMemsetAsync(cellOfs, 0, 2048 * sizeof(int), stream);
  hipLaunchKernelGGL(prep_kernel, dim3(9), dim3(256), 0, stream, pa, AF, biasAll);
  hipLaunchKernelGGL(pos4cid_kernel, dim3(B * N / 256), dim3(256), 0, stream,
                     pos, pos4, cid16, cellCount);
  hipLaunchKernelGGL(scan_kernel, dim3(1), dim3(1024), 0, stream, cellCount, cellStart);
  hipLaunchKernelGGL(scatter_kernel, dim3(B * N / 256), dim3(256), 0, stream,
                     pos4, cid16, cellStart, cellOfs, pos4s, sid);
  hipLaunchKernelGGL(qkv_kernel, dim3(128), dim3(256), 0, stream,
                     feats, (const int4*)wsb, biasAll, qTb, kTb, vTb);
  hipLaunchKernelGGL(knn_shell_kernel, dim3(B * N / 4), dim3(256), 0, stream,
                     pos4s, sid, cellStart, knn);
  hipLaunchKernelGGL(fused_kernel, dim3(2048), dim3(256), 0, stream,
                     (const float4*)pos4, knn, qTb, kTb, vTb,
                     (const int4*)(wsb + 32768), biasAll + 64, res_ws);
  hipLaunchKernelGGL(final_kernel, dim3(128), dim3(256), 0, stream,
                     res_ws, (const int4*)(wsb + 59392), biasAll + 256, feats, (float*)d_out);
}

// Round 7
// 151.161 us; speedup vs baseline: 3.2456x; 1.1858x over previous
//
#include <hip/hip_runtime.h>
#include <hip/hip_bf16.h>
#include <math.h>

namespace {

constexpr int B = 2;
constexpr int N = 8192;
constexpr int D = 64;
constexpr int GRID = 10;
constexpr int GC = GRID * GRID * GRID;     // 1000 cells per batch
constexpr float H = 0.1f;
constexpr float NEGS = 0.2f;
constexpr float BN_INV = 0.9999950000374997f;   // 1/sqrt(1+1e-5)
constexpr float RSQN = 0.011048543456039806f;   // 1/sqrt(8192)

typedef __attribute__((ext_vector_type(8))) short bf16x8;
typedef __attribute__((ext_vector_type(16))) float f32x16;

union Frag { int4 i4; unsigned u[4]; bf16x8 h; };

__device__ __forceinline__ float lrelu(float v) { return v > 0.f ? v : NEGS * v; }

__device__ __forceinline__ unsigned pk2(float a, float b) {
  __hip_bfloat162 h2 = __float22bfloat162_rn(make_float2(a, b));
  unsigned r;
  __builtin_memcpy(&r, &h2, 4);
  return r;
}
__device__ __forceinline__ float blo(unsigned u) { return __uint_as_float(u << 16); }
__device__ __forceinline__ float bhi(unsigned u) { return __uint_as_float(u & 0xFFFF0000u); }

__device__ __forceinline__ f32x16 MF(int4 a, const Frag& b, f32x16 c) {
  Frag af; af.i4 = a;
  return __builtin_amdgcn_mfma_f32_32x32x16_bf16(af.h, b.h, c, 0, 0, 0);
}

__device__ __forceinline__ int cellco(float v) {
  int c = (int)(v * 10.0f);
  return min(max(c, 0), GRID - 1);
}

// D-layout f32 (x0: chans 0-31 rows, x1: chans 32-63) -> B-fragments for next layer.
__device__ __forceinline__ void buildB(const f32x16& x0, const f32x16& x1, int h, Frag Bf[4]) {
  unsigned Z[8][2];
  #pragma unroll
  for (int q = 0; q < 4; ++q) {
    Z[q][0]     = pk2(x0[4*q+0], x0[4*q+1]);
    Z[q][1]     = pk2(x0[4*q+2], x0[4*q+3]);
    Z[4+q][0]   = pk2(x1[4*q+0], x1[4*q+1]);
    Z[4+q][1]   = pk2(x1[4*q+2], x1[4*q+3]);
  }
  unsigned S[8][2];
  #pragma unroll
  for (int q = 0; q < 8; ++q) {
    S[q][0] = (unsigned)__shfl_xor((int)Z[q][0], 32);
    S[q][1] = (unsigned)__shfl_xor((int)Z[q][1], 32);
  }
  #pragma unroll
  for (int t = 0; t < 4; ++t) {
    int qq = (t >> 1) * 4 + 2 * (t & 1);
    Bf[t].u[0] = h ? S[qq+1][0] : Z[qq][0];
    Bf[t].u[1] = h ? S[qq+1][1] : Z[qq][1];
    Bf[t].u[2] = h ? Z[qq+1][0] : S[qq][0];
    Bf[t].u[3] = h ? Z[qq+1][1] : S[qq][1];
  }
}

__device__ __forceinline__ f32x16 biasAct(f32x16 d, const float4* bp, int mt, int h) {
  f32x16 r;
  #pragma unroll
  for (int q = 0; q < 4; ++q) {
    float4 bb = bp[h * 8 + mt * 4 + q];
    r[4*q+0] = lrelu(d[4*q+0] + bb.x);
    r[4*q+1] = lrelu(d[4*q+1] + bb.y);
    r[4*q+2] = lrelu(d[4*q+2] + bb.z);
    r[4*q+3] = lrelu(d[4*q+3] + bb.w);
  }
  return r;
}

// ---------------- prep: pack A-fragments (bf16, BN scale folded) + permuted biases ----------------
struct PrepArgs {
  const float* W[9];       // W1,Wq,Wk,Wv,Wd2,Wg1,Wg2,W2,Wd1
  const float* scale[9];
  const float* bias[5];    // b1,bd2,bg1,bg2,b2
  const float* bd1;
};

__global__ __launch_bounds__(256) void prep_kernel(PrepArgs a, unsigned short* AF, float* biasAll) {
  int mi = blockIdx.x;
  int tid = threadIdx.x;
  if (mi < 8) {
    int off = (mi == 7) ? 29696 : mi * 4096;
    const float* W = a.W[mi];
    const float* G = a.scale[mi];
    unsigned short* dst = AF + off;
    for (int e = tid; e < 4096; e += 256) {
      int i = e & 7, lane = (e >> 3) & 63, t = (e >> 9) & 3, mt = e >> 11;
      int row = 32 * mt + (lane & 31);
      int k = 16 * t + 8 * (lane >> 5) + i;
      float v = W[row * 64 + k];
      if (G) v *= G[row] * BN_INV;
      __hip_bfloat16 hb = __float2bfloat16(v);
      __builtin_memcpy(&dst[e], &hb, 2);
    }
  } else {
    const float* W = a.W[8];
    const float* G = a.scale[8];
    for (int e = tid; e < 1024; e += 256) {
      int i = e & 7, lane = (e >> 3) & 63, mt = e >> 9;
      int row = 32 * mt + (lane & 31), h = lane >> 5;
      float v = 0.f;
      if (h == 0) {
        if (i < 3) v = W[row * 3 + i] * G[row] * BN_INV;
        else if (i == 3) v = a.bd1[row];
      }
      __hip_bfloat16 hb = __float2bfloat16(v);
      __builtin_memcpy(&AF[28672 + e], &hb, 2);
    }
    for (int e = tid; e < 320; e += 256) {
      int ai = e >> 6, idx = e & 63;
      int h = idx >> 5, mt = (idx >> 4) & 1, q = (idx >> 2) & 3, j = idx & 3;
      biasAll[e] = a.bias[ai][32 * mt + 8 * q + 4 * h + j];
    }
  }
}

// ---------------- pos4 + cell id + histogram ----------------
__global__ __launch_bounds__(256) void pos4cid_kernel(
    const float* __restrict__ pos, float* __restrict__ pos4,
    int* __restrict__ cid16, int* __restrict__ cellCount)
{
  int i = blockIdx.x * 256 + threadIdx.x;
  int b = i >> 13;
  int n = i & (N - 1);
  const float* pb = pos + (size_t)b * 3 * N;
  float x = pb[n], y = pb[N + n], z = pb[2 * N + n];
  float4 v = {x, y, z, x * x + y * y + z * z};
  *reinterpret_cast<float4*>(pos4 + (size_t)i * 4) = v;
  int cid = (cellco(z) * GRID + cellco(y)) * GRID + cellco(x);
  cid16[i] = cid;
  atomicAdd(&cellCount[b * GC + cid], 1);
}

// ---------------- scan: exclusive prefix over 2048 cell counts (single block) ----------------
__global__ __launch_bounds__(1024) void scan_kernel(
    const int* __restrict__ cnt, int* __restrict__ cellStart)
{
  __shared__ int s[2][2048];
  int t = threadIdx.x;
  s[0][t] = cnt[t];
  s[0][t + 1024] = cnt[t + 1024];
  __syncthreads();
  int src = 0;
  for (int off = 1; off < 2048; off <<= 1) {
    int dst = src ^ 1;
    for (int i = t; i < 2048; i += 1024) {
      int v = s[src][i];
      if (i >= off) v += s[src][i - off];
      s[dst][i] = v;
    }
    __syncthreads();
    src ^= 1;
  }
  cellStart[t] = (t == 0) ? 0 : s[src][t - 1];
  cellStart[t + 1024] = s[src][t + 1023];
}

// ---------------- scatter: counting-sort points by cell ----------------
__global__ __launch_bounds__(256) void scatter_kernel(
    const float* __restrict__ pos4, const int* __restrict__ cid16,
    const int* __restrict__ cellStart, int* __restrict__ cellOfs,
    float4* __restrict__ pos4s, int* __restrict__ sid)
{
  int i = blockIdx.x * 256 + threadIdx.x;
  int b = i >> 13;
  int cg = b * GC + cid16[i];
  int dst = cellStart[cg] + atomicAdd(&cellOfs[cg], 1);
  pos4s[dst] = *reinterpret_cast<const float4*>(pos4 + (size_t)i * 4);
  sid[dst] = i & (N - 1);
}

// ---------------- knn: 16-lane group per query (4 queries/wave); shell + margin cert ----------------
// Group's 16 lanes stride the candidates of each (z,y) row of the (2r+1)^3 window; per-lane
// sorted top-16 (u64 keys dist|sid = exact reference tie-break); 16 rounds of group-min
// extraction (xor masks 1..8 stay in-group -> 4 queries extracted simultaneously per wave).
// Margin certificate per group; rare failures rescan at r+1 under exec mask.
__global__ __launch_bounds__(256) void knn_shell_kernel(
    const float4* __restrict__ pos4s, const int* __restrict__ sid,
    const int* __restrict__ cellStart, int* __restrict__ knn)
{
  constexpr unsigned long long SENT = 0x7F7FFFFFFFFFFFFFULL;  // FLT_MAX | idx mask
  int lq = threadIdx.x & 15;                          // lane within group
  int wid = (blockIdx.x * 256 + threadIdx.x) >> 4;    // group id = sorted slot = query
  int b = wid >> 13;
  float4 q = pos4s[wid];
  int myid = sid[wid];
  int cx = cellco(q.x), cy = cellco(q.y), cz = cellco(q.z);
  const int cbase = b * GC;
  int* orow = knn + ((size_t)b * N + myid) * 16;

  bool done = false;
  #pragma unroll 1
  for (int r = 1; r < GRID; ++r) {
    if (!done) {
      unsigned long long dk[16];
      #pragma unroll
      for (int j = 0; j < 16; ++j) dk[j] = SENT;

      int x0 = max(cx - r, 0), x1 = min(cx + r, GRID - 1);
      int y0 = max(cy - r, 0), y1 = min(cy + r, GRID - 1);
      int z0 = max(cz - r, 0), z1 = min(cz + r, GRID - 1);
      #pragma unroll 1
      for (int zz = z0; zz <= z1; ++zz) {
        #pragma unroll 1
        for (int yy = y0; yy <= y1; ++yy) {
          int rowc = cbase + (zz * GRID + yy) * GRID;
          int i0 = cellStart[rowc + x0], i1 = cellStart[rowc + x1 + 1];
          #pragma unroll 1
          for (int i = i0 + lq; i < i1; i += 16) {
            float4 cp = pos4s[i];
            float inn = q.x * cp.x + q.y * cp.y + q.z * cp.z;
            float dist = fmaxf(fmaf(-2.f, inn, q.w + cp.w), 0.f);
            unsigned long long key =
                ((unsigned long long)__float_as_uint(dist) << 32) | (unsigned)sid[i];
            if (key < dk[15]) {
              bool bj = true;
              #pragma unroll
              for (int j = 15; j >= 1; --j) {
                bool bjm1 = key < dk[j - 1];
                dk[j] = bj ? (bjm1 ? dk[j - 1] : key) : dk[j];
                bj = bjm1;
              }
              if (bj) dk[0] = key;
            }
          }
        }
      }

      // extract group top-16 (merge 16 sorted lists), write as we go
      float dlast = 0.f;
      #pragma unroll 1
      for (int e = 0; e < 16; ++e) {
        unsigned long long m = dk[0];
        #pragma unroll
        for (int msk = 1; msk <= 8; msk <<= 1) {
          unsigned long long o = __shfl_xor(m, msk);
          m = (o < m) ? o : m;
        }
        if (dk[0] == m) {                      // unique winner (keys embed unique sid)
          #pragma unroll
          for (int j = 0; j < 15; ++j) dk[j] = dk[j + 1];
          dk[15] = SENT;
        }
        if (lq == 0) orow[e] = (int)(m & 0xFFFFFFFFULL);
        dlast = __uint_as_float((unsigned)(m >> 32));
      }

      // margin certificate from searched window (domain faces -> inf)
      float mg = 3.4e38f;
      if (cx - r > 0)        mg = fminf(mg, q.x - (cx - r) * H);
      if (cx + r < GRID - 1) mg = fminf(mg, (cx + r + 1) * H - q.x);
      if (cy - r > 0)        mg = fminf(mg, q.y - (cy - r) * H);
      if (cy + r < GRID - 1) mg = fminf(mg, (cy + r + 1) * H - q.y);
      if (cz - r > 0)        mg = fminf(mg, q.z - (cz - r) * H);
      if (cz + r < GRID - 1) mg = fminf(mg, (cz + r + 1) * H - q.z);
      done = (dlast <= mg * mg * 0.999f);      // group-uniform
    }
    if (__all(done)) break;
  }
}

// ---------------- qkv (MFMA): X = lrelu(bn(W1@feats)); q/k/v = W@X stored bf16 [pt][64] ----------------
__global__ __launch_bounds__(256) void qkv_kernel(
    const float* __restrict__ feats, const int4* __restrict__ AF,
    const float* __restrict__ b1p,
    uint2* __restrict__ qT, uint2* __restrict__ kT, uint2* __restrict__ vT)
{
  __shared__ int4 sA[2048];   // W1 | Wq | Wk | Wv
  for (int i = threadIdx.x; i < 2048; i += 256) sA[i] = AF[i];
  __syncthreads();
  int lane = threadIdx.x & 63, w = threadIdx.x >> 6;
  int gw = blockIdx.x * 4 + w;
  int col = lane & 31, h = lane >> 5;
  int nb = gw * 32;
  int b = nb >> 13;
  int n = (nb & (N - 1)) + col;
  size_t gpt = (size_t)b * N + n;
  const float* fb = feats + (size_t)b * D * N + n;

  Frag Bf[4];
  #pragma unroll
  for (int t = 0; t < 4; ++t) {
    int c0 = 16 * t + 8 * h;
    float f[8];
    #pragma unroll
    for (int i = 0; i < 8; ++i) f[i] = fb[(size_t)(c0 + i) * N];
    #pragma unroll
    for (int d_ = 0; d_ < 4; ++d_) Bf[t].u[d_] = pk2(f[2*d_], f[2*d_+1]);
  }
  f32x16 acc0 = {}, acc1 = {};
  #pragma unroll
  for (int t = 0; t < 4; ++t) {
    acc0 = MF(sA[t * 64 + lane], Bf[t], acc0);
    acc1 = MF(sA[(4 + t) * 64 + lane], Bf[t], acc1);
  }
  const float4* bp = (const float4*)b1p;
  f32x16 x0 = biasAct(acc0, bp, 0, h);
  f32x16 x1 = biasAct(acc1, bp, 1, h);
  Frag Bx[4];
  buildB(x0, x1, h, Bx);

  #pragma unroll
  for (int mmat = 0; mmat < 3; ++mmat) {
    const int4* Am = sA + 512 * (mmat + 1);
    uint2* op = (mmat == 0) ? qT : (mmat == 1) ? kT : vT;
    f32x16 a0 = {}, a1 = {};
    #pragma unroll
    for (int t = 0; t < 4; ++t) {
      a0 = MF(Am[t * 64 + lane], Bx[t], a0);
      a1 = MF(Am[(4 + t) * 64 + lane], Bx[t], a1);
    }
    #pragma unroll
    for (int q = 0; q < 4; ++q) {
      uint2 v0, v1;
      v0.x = pk2(a0[4*q+0], a0[4*q+1]); v0.y = pk2(a0[4*q+2], a0[4*q+3]);
      v1.x = pk2(a1[4*q+0], a1[4*q+1]); v1.y = pk2(a1[4*q+2], a1[4*q+3]);
      op[gpt * 16 + 2 * q + h] = v0;
      op[gpt * 16 + 8 + 2 * q + h] = v1;
    }
  }
}

// ---------------- fused (MFMA): pe -> pos_enc -> a0 -> a1 -> a2 -> softmax -> res ----------------
__global__ __launch_bounds__(256) void fused_kernel(
    const float4* __restrict__ pos4, const int* __restrict__ knn,
    const uint2* __restrict__ qT, const uint2* __restrict__ kT, const uint2* __restrict__ vT,
    const int4* __restrict__ AF,      // [Wd2 | Wg1 | Wg2 | Wd1]
    const float* __restrict__ biases, // bd2p | bg1p | bg2p
    float* __restrict__ res_ws)
{
  __shared__ int4 sA[1664];
  for (int i = threadIdx.x; i < 1664; i += 256) sA[i] = AF[i];
  __syncthreads();
  const float4* bpd2 = (const float4*)(biases);
  const float4* bpg1 = (const float4*)(biases + 64);
  const float4* bpg2 = (const float4*)(biases + 128);

  int lane = threadIdx.x & 63, w = threadIdx.x >> 6;
  int gw = blockIdx.x * 4 + w;
  int col = lane & 31, h = lane >> 5;
  int p = col >> 4, kk = col & 15;
  int pbase = gw * 2;
  int b = pbase >> 13;
  int n = (pbase & (N - 1)) + p;
  size_t g = (size_t)b * N + n;
  int m = knn[g * 16 + kk];
  size_t gm = (size_t)b * N + m;

  float4 P = pos4[g], Q = pos4[gm];
  float rx = P.x - Q.x, ry = P.y - Q.y, rz = P.z - Q.z;

  // L0: pe = lrelu(s*Wd1@rel + bd1)   (bias via B k=3 column)
  Frag B0;
  B0.u[0] = h ? 0u : pk2(rx, ry);
  B0.u[1] = h ? 0u : pk2(rz, 1.0f);
  B0.u[2] = 0u; B0.u[3] = 0u;
  f32x16 acc0 = {}, acc1 = {};
  acc0 = MF(sA[1536 + lane], B0, acc0);
  acc1 = MF(sA[1536 + 64 + lane], B0, acc1);
  f32x16 pe0, pe1;
  #pragma unroll
  for (int i = 0; i < 16; ++i) { pe0[i] = lrelu(acc0[i]); pe1[i] = lrelu(acc1[i]); }
  Frag Bp[4];
  buildB(pe0, pe1, h, Bp);

  // L1: pos_enc = lrelu(s*Wd2@pe + bd2)
  acc0 = (f32x16){}; acc1 = (f32x16){};
  #pragma unroll
  for (int t = 0; t < 4; ++t) {
    acc0 = MF(sA[t * 64 + lane], Bp[t], acc0);
    acc1 = MF(sA[(4 + t) * 64 + lane], Bp[t], acc1);
  }
  f32x16 pn0 = biasAct(acc0, bpd2, 0, h);
  f32x16 pn1 = biasAct(acc1, bpd2, 1, h);

  unsigned pep[8][2];
  #pragma unroll
  for (int q = 0; q < 4; ++q) {
    pep[q][0]   = pk2(pn0[4*q+0], pn0[4*q+1]);
    pep[q][1]   = pk2(pn0[4*q+2], pn0[4*q+3]);
    pep[4+q][0] = pk2(pn1[4*q+0], pn1[4*q+1]);
    pep[4+q][1] = pk2(pn1[4*q+2], pn1[4*q+3]);
  }

  // a0 = q[n] - k[m] + pos_enc
  f32x16 av0, av1;
  #pragma unroll
  for (int mt = 0; mt < 2; ++mt) {
    f32x16& dst = mt ? av1 : av0;
    const f32x16& pn = mt ? pn1 : pn0;
    #pragma unroll
    for (int q = 0; q < 4; ++q) {
      uint2 qv = qT[g * 16 + 8 * mt + 2 * q + h];
      uint2 kv = kT[gm * 16 + 8 * mt + 2 * q + h];
      dst[4*q+0] = pn[4*q+0] + blo(qv.x) - blo(kv.x);
      dst[4*q+1] = pn[4*q+1] + bhi(qv.x) - bhi(kv.x);
      dst[4*q+2] = pn[4*q+2] + blo(qv.y) - blo(kv.y);
      dst[4*q+3] = pn[4*q+3] + bhi(qv.y) - bhi(kv.y);
    }
  }
  buildB(av0, av1, h, Bp);

  // L2: a1 = lrelu(s*Wg1@a0 + bg1)
  acc0 = (f32x16){}; acc1 = (f32x16){};
  #pragma unroll
  for (int t = 0; t < 4; ++t) {
    acc0 = MF(sA[512 + t * 64 + lane], Bp[t], acc0);
    acc1 = MF(sA[512 + (4 + t) * 64 + lane], Bp[t], acc1);
  }
  f32x16 a10 = biasAct(acc0, bpg1, 0, h);
  f32x16 a11 = biasAct(acc1, bpg1, 1, h);
  buildB(a10, a11, h, Bp);

  // L3: a2 = lrelu(s*Wg2@a1 + bg2) * RSQN
  acc0 = (f32x16){}; acc1 = (f32x16){};
  #pragma unroll
  for (int t = 0; t < 4; ++t) {
    acc0 = MF(sA[1024 + t * 64 + lane], Bp[t], acc0);
    acc1 = MF(sA[1024 + (4 + t) * 64 + lane], Bp[t], acc1);
  }
  f32x16 at0 = biasAct(acc0, bpg2, 0, h);
  f32x16 at1 = biasAct(acc1, bpg2, 1, h);
  #pragma unroll
  for (int i = 0; i < 16; ++i) { at0[i] *= RSQN; at1[i] *= RSQN; }

  // softmax over kk + weighted sum of vpe = v + pos_enc
  float* rp = res_ws + g * 64;
  #pragma unroll
  for (int mt = 0; mt < 2; ++mt) {
    const f32x16& at = mt ? at1 : at0;
    f32x16 ev, nm;
    #pragma unroll
    for (int q = 0; q < 4; ++q) {
      uint2 vv = vT[gm * 16 + 8 * mt + 2 * q + h];
      unsigned pp0 = pep[mt * 4 + q][0], pp1 = pep[mt * 4 + q][1];
      float vp0 = blo(vv.x) + blo(pp0);
      float vp1 = bhi(vv.x) + bhi(pp0);
      float vp2 = blo(vv.y) + blo(pp1);
      float vp3 = bhi(vv.y) + bhi(pp1);
      ev[4*q+0] = __expf(at[4*q+0]); nm[4*q+0] = ev[4*q+0] * vp0;
      ev[4*q+1] = __expf(at[4*q+1]); nm[4*q+1] = ev[4*q+1] * vp1;
      ev[4*q+2] = __expf(at[4*q+2]); nm[4*q+2] = ev[4*q+2] * vp2;
      ev[4*q+3] = __expf(at[4*q+3]); nm[4*q+3] = ev[4*q+3] * vp3;
    }
    #pragma unroll
    for (int i = 0; i < 16; ++i) {
      #pragma unroll
      for (int mask = 1; mask <= 8; mask <<= 1) {
        ev[i] += __shfl_xor(ev[i], mask);
        nm[i] += __shfl_xor(nm[i], mask);
      }
    }
    if (kk == 0) {
      #pragma unroll
      for (int q = 0; q < 4; ++q) {
        float4 r;
        r.x = nm[4*q+0] / ev[4*q+0];
        r.y = nm[4*q+1] / ev[4*q+1];
        r.z = nm[4*q+2] / ev[4*q+2];
        r.w = nm[4*q+3] / ev[4*q+3];
        *(float4*)(rp + 32 * mt + 8 * q + 4 * h) = r;
      }
    }
  }
}

// ---------------- final (MFMA): out = lrelu(bn(W2@res)) + feats ----------------
__global__ __launch_bounds__(256) void final_kernel(
    const float* __restrict__ res_ws, const int4* __restrict__ AF,
    const float* __restrict__ b2p, const float* __restrict__ feats,
    float* __restrict__ out)
{
  __shared__ int4 sA[512];
  for (int i = threadIdx.x; i < 512; i += 256) sA[i] = AF[i];
  __syncthreads();
  int lane = threadIdx.x & 63, w = threadIdx.x >> 6;
  int gw = blockIdx.x * 4 + w;
  int col = lane & 31, h = lane >> 5;
  int nb = gw * 32;
  int b = nb >> 13;
  int n = (nb & (N - 1)) + col;
  size_t g = (size_t)b * N + n;
  const float* rp = res_ws + g * 64;
  Frag Br[4];
  #pragma unroll
  for (int t = 0; t < 4; ++t) {
    float4 r0 = *(const float4*)(rp + 16 * t + 8 * h);
    float4 r1 = *(const float4*)(rp + 16 * t + 8 * h + 4);
    Br[t].u[0] = pk2(r0.x, r0.y); Br[t].u[1] = pk2(r0.z, r0.w);
    Br[t].u[2] = pk2(r1.x, r1.y); Br[t].u[3] = pk2(r1.z, r1.w);
  }
  f32x16 a0 = {}, a1 = {};
  #pragma unroll
  for (int t = 0; t < 4; ++t) {
    a0 = MF(sA[t * 64 + lane], Br[t], a0);
    a1 = MF(sA[(4 + t) * 64 + lane], Br[t], a1);
  }
  const float4* bp = (const float4*)b2p;
  f32x16 o0 = biasAct(a0, bp, 0, h);
  f32x16 o1 = biasAct(a1, bp, 1, h);
  const float* fb = feats + (size_t)b * D * N;
  float* ob = out + (size_t)b * D * N;
  #pragma unroll
  for (int mt = 0; mt < 2; ++mt) {
    const f32x16& oo = mt ? o1 : o0;
    #pragma unroll
    for (int q = 0; q < 4; ++q) {
      #pragma unroll
      for (int j = 0; j < 4; ++j) {
        int chan = 32 * mt + 8 * q + 4 * h + j;
        ob[(size_t)chan * N + n] = oo[4*q+j] + fb[(size_t)chan * N + n];
      }
    }
  }
}

} // namespace

extern "C" void kernel_launch(void* const* d_in, const int* in_sizes, int n_in,
                              void* d_out, int out_size, void* d_ws, size_t ws_size,
                              hipStream_t stream) {
  const float* feats = (const float*)d_in[0];
  const float* pos   = (const float*)d_in[1];
  const float* W1  = (const float*)d_in[3];
  const float* g1  = (const float*)d_in[4];
  const float* b1  = (const float*)d_in[5];
  const float* Wq  = (const float*)d_in[6];
  const float* Wk  = (const float*)d_in[7];
  const float* Wv  = (const float*)d_in[8];
  const float* Wd1 = (const float*)d_in[9];
  const float* gd1 = (const float*)d_in[10];
  const float* bd1 = (const float*)d_in[11];
  const float* Wd2 = (const float*)d_in[12];
  const float* gd2 = (const float*)d_in[13];
  const float* bd2 = (const float*)d_in[14];
  const float* Wg1 = (const float*)d_in[15];
  const float* gg1 = (const float*)d_in[16];
  const float* bg1 = (const float*)d_in[17];
  const float* Wg2 = (const float*)d_in[18];
  const float* gg2 = (const float*)d_in[19];
  const float* bg2 = (const float*)d_in[20];
  const float* W2  = (const float*)d_in[21];
  const float* g2  = (const float*)d_in[22];
  const float* b2  = (const float*)d_in[23];

  uint8_t* wsb = (uint8_t*)d_ws;
  unsigned short* AF = (unsigned short*)wsb;               // bf16 A-frags (73728 B reserved)
  float* biasAll = (float*)(wsb + 73728);                  // 320 floats
  float* pos4    = (float*)(wsb + 75008);                  // 65536 floats (256 KB)
  uint2* qTb     = (uint2*)(wsb + 337152);                 // 2 MB
  uint2* kTb     = (uint2*)(wsb + 2434304);                // 2 MB
  uint2* vTb     = (uint2*)(wsb + 4531456);                // 2 MB
  float* res_ws  = (float*)(wsb + 6628608);                // 4 MB
  int*   cid16     = (int*)(wsb + 10822912);               // 64 KB
  int*   cellCount = (int*)(wsb + 10888448);               // 8 KB (2048)
  int*   cellStart = (int*)(wsb + 10896640);               // 8 KB (2048+1)
  int*   cellOfs   = (int*)(wsb + 10904832);               // 8 KB (2048)
  float4* pos4s    = (float4*)(wsb + 10913024);            // 256 KB
  int*   sid       = (int*)(wsb + 11175168);               // 64 KB
  int*   knn       = (int*)(wsb + 11240704);               // 1 MB (16384*16*4)

  PrepArgs pa;
  pa.W[0] = W1;  pa.W[1] = Wq;  pa.W[2] = Wk;  pa.W[3] = Wv;
  pa.W[4] = Wd2; pa.W[5] = Wg1; pa.W[6] = Wg2; pa.W[7] = W2; pa.W[8] = Wd1;
  pa.scale[0] = g1;  pa.scale[1] = nullptr; pa.scale[2] = nullptr; pa.scale[3] = nullptr;
  pa.scale[4] = gd2; pa.scale[5] = gg1;     pa.scale[6] = gg2;     pa.scale[7] = g2; pa.scale[8] = gd1;
  pa.bias[0] = b1; pa.bias[1] = bd2; pa.bias[2] = bg1; pa.bias[3] = bg2; pa.bias[4] = b2;
  pa.bd1 = bd1;

  hipMemsetAsync(cellCount, 0, 2048 * sizeof(int), stream);
  hipMemsetAsync(cellOfs, 0, 2048 * sizeof(int), stream);
  hipLaunchKernelGGL(prep_kernel, dim3(9), dim3(256), 0, stream, pa, AF, biasAll);
  hipLaunchKernelGGL(pos4cid_kernel, dim3(B * N / 256), dim3(256), 0, stream,
                     pos, pos4, cid16, cellCount);
  hipLaunchKernelGGL(scan_kernel, dim3(1), dim3(1024), 0, stream, cellCount, cellStart);
  hipLaunchKernelGGL(scatter_kernel, dim3(B * N / 256), dim3(256), 0, stream,
                     pos4, cid16, cellStart, cellOfs, pos4s, sid);
  hipLaunchKernelGGL(qkv_kernel, dim3(128), dim3(256), 0, stream,
                     feats, (const int4*)wsb, biasAll, qTb, kTb, vTb);
  hipLaunchKernelGGL(knn_shell_kernel, dim3(B * N / 16), dim3(256), 0, stream,
                     pos4s, sid, cellStart, knn);
  hipLaunchKernelGGL(fused_kernel, dim3(2048), dim3(256), 0, stream,
                     (const float4*)pos4, knn, qTb, kTb, vTb,
                     (const int4*)(wsb + 32768), biasAll + 64, res_ws);
  hipLaunchKernelGGL(final_kernel, dim3(128), dim3(256), 0, stream,
                     res_ws, (const int4*)(wsb + 59392), biasAll + 256, feats, (float*)d_out);
}